// Round 18
// baseline (50.806 us; speedup 1.0000x reference)
//
#include <hip/hip_runtime.h>
#include <hip/hip_fp16.h>

#define NCITY 384
#define BATCH 4
#define DIM   128
#define HID   256
#define M_TOT 1536

typedef unsigned short u16;
typedef _Float16 f16x8 __attribute__((ext_vector_type(8)));
typedef float f32x4 __attribute__((ext_vector_type(4)));

// ---------------------------------------------------------------------------
// helpers
// ---------------------------------------------------------------------------
__device__ __forceinline__ unsigned pk_add(unsigned a, unsigned b) {
    unsigned r; asm("v_pk_add_f16 %0, %1, %2" : "=v"(r) : "v"(a), "v"(b)); return r;
}
__device__ __forceinline__ unsigned pk_max0(unsigned a) {
    unsigned r; asm("v_pk_max_f16 %0, %1, %2" : "=v"(r) : "v"(a), "v"(0u)); return r;
}
__device__ __forceinline__ unsigned pk_fma(unsigned a, unsigned b, unsigned c) {
    unsigned r; asm("v_pk_fma_f16 %0, %1, %2, %3" : "=v"(r) : "v"(a), "v"(b), "v"(c)); return r;
}
__device__ __forceinline__ unsigned pack2(float a, float b) {
    union { __half2 h2; unsigned u; } c;
    c.h2 = __float22half2_rn(make_float2(a, b));
    return c.u;
}
__device__ __forceinline__ float sum2(unsigned u) {
    union { unsigned u; __half2 h2; } c; c.u = u;
    return __low2float(c.h2) + __high2float(c.h2);
}
__device__ __forceinline__ u16 h_bits(float x) {
    union { __half h; u16 s; } c;
    c.h = __float2half(x);
    return c.s;
}
union H8 { float4 f4; unsigned u[4]; };

// ---------------------------------------------------------------------------
// K1: MFMA encoder. 24 blocks x 256 thr (4 waves), 64 rows/block.
// LDS: A1 h1[64][256] f16 32KB + B[·] 64KB + A2 emb[64][128] f16 16KB.
// XOR swizzle (16B unit u at u^(row&15)) on all tiles — pair-kernel-proven.
// Frags (16x16x32_f16): A lane l: row=l&15, k=(l>>4)*8+j; B: col=l&15, same k;
// C/D: col=l&15, row=(l>>4)*4+reg  [guide m89-verified].
// ---------------------------------------------------------------------------
__global__ __launch_bounds__(256) void encoder_mfma(
    const float* __restrict__ cities,
    const float* __restrict__ We1, const float* __restrict__ be1,
    const float* __restrict__ We2, const float* __restrict__ be2,
    const float* __restrict__ Wa1, const float* __restrict__ ba1,
    const float* __restrict__ wa2, const float* __restrict__ ba2,
    const float* __restrict__ Wd1, const float* __restrict__ bd1,
    float* __restrict__ score, u16* __restrict__ Ai_u, u16* __restrict__ Aj_u)
{
    __shared__ __align__(16) u16 A1[64 * 256];   // 32 KB
    __shared__ __align__(16) u16 Bs[32768];      // 64 KB (We2 / Wh chunk)
    __shared__ __align__(16) u16 A2[64 * 128];   // 16 KB
    __shared__ float cit_s[128];
    __shared__ float be2_s[128];
    __shared__ float score_s[64];

    const int tid = threadIdx.x;
    const int w   = tid >> 6;        // wave = row-tile mt
    const int l   = tid & 63;
    const int r0  = blockIdx.x * 64;

    if (tid < 128) {
        cit_s[tid] = cities[r0 * 2 + tid];
        be2_s[tid] = be2[tid];
    }

    // ---- stage We2 [256k][128n] f32 -> Bs[n][k] f16 (k-pairs packed b32) ----
    {
        unsigned* B32 = (unsigned*)Bs;
        #pragma unroll
        for (int i = 0; i < 16; ++i) {
            const int pidx = i * 256 + tid;          // 4096 (k2, n4) pairs
            const int k2 = pidx >> 5;                // 0..127 (k = 2k2, 2k2+1)
            const int n4 = pidx & 31;
            const float4 w0 = ((const float4*)We2)[(2 * k2) * 32 + n4];
            const float4 w1 = ((const float4*)We2)[(2 * k2 + 1) * 32 + n4];
            #pragma unroll
            for (int c = 0; c < 4; ++c) {
                const int n = n4 * 4 + c;
                const unsigned v = pack2((&w0.x)[c], (&w1.x)[c]);
                B32[n * 64 + (((k2 >> 2) ^ (n & 15)) * 4) + (k2 & 3)] = v;
            }
        }
    }
    __syncthreads();     // cit_s ready (Bs writes also done)

    // ---- h1 = relu(cities@We1+be1) -> A1 (thread owns k = tid) -------------
    {
        const float w0 = We1[tid], w1 = We1[HID + tid], b1v = be1[tid];
        #pragma unroll 8
        for (int m = 0; m < 64; ++m) {
            const float v = fmaxf(fmaf(cit_s[2 * m], w0,
                                  fmaf(cit_s[2 * m + 1], w1, b1v)), 0.f);
            A1[m * 256 + (((tid >> 3) ^ (m & 15)) * 8) + (tid & 7)] = h_bits(v);
        }
    }
    __syncthreads();     // A1 + Bs ready

    // ---- emb = A1 @ We2 + be2 -> A2 ----------------------------------------
    {
        const int mrow = w * 16 + (l & 15);
        f16x8 af[8];
        #pragma unroll
        for (int kst = 0; kst < 8; ++kst)
            af[kst] = *(const f16x8*)&A1[mrow * 256 + (((kst * 4 + (l >> 4)) ^ (l & 15)) * 8)];
        #pragma unroll
        for (int nt = 0; nt < 8; ++nt) {
            f32x4 acc = {0.f, 0.f, 0.f, 0.f};
            #pragma unroll
            for (int kst = 0; kst < 8; ++kst) {
                const f16x8 bf = *(const f16x8*)&Bs[(nt * 16 + (l & 15)) * 256
                                    + (((kst * 4 + (l >> 4)) ^ (l & 15)) * 8)];
                acc = __builtin_amdgcn_mfma_f32_16x16x32_f16(af[kst], bf, acc, 0, 0, 0);
            }
            const int col = nt * 16 + (l & 15);
            #pragma unroll
            for (int i = 0; i < 4; ++i) {
                const int row = w * 16 + (l >> 4) * 4 + i;
                const float v = acc[i] + be2_s[col];
                A2[row * 128 + (((col >> 3) ^ (row & 15)) * 8) + (col & 7)] = h_bits(v);
            }
        }
    }
    __syncthreads();     // A2 ready; Bs reads done

    // ---- heads: 3 chunks (att / Ai / Aj), each B = [128k][256n] ------------
    float rs[4] = {0.f, 0.f, 0.f, 0.f};
    const int mrow = w * 16 + (l & 15);

    for (int ch = 0; ch < 3; ++ch) {
        // stage chunk -> Bs[n][128k] f16 (k-pairs packed b32)
        {
            const float* src = (ch == 0) ? Wa1 : Wd1 + (ch - 1) * (DIM * HID);
            unsigned* B32 = (unsigned*)Bs;
            #pragma unroll
            for (int i = 0; i < 16; ++i) {
                const int pidx = i * 256 + tid;      // 4096 (k2, n4) pairs
                const int k2 = pidx >> 6;            // 0..63 (k = 2k2, 2k2+1)
                const int n4 = pidx & 63;
                const float4 w0 = ((const float4*)src)[(2 * k2) * 64 + n4];
                const float4 w1 = ((const float4*)src)[(2 * k2 + 1) * 64 + n4];
                #pragma unroll
                for (int c = 0; c < 4; ++c) {
                    const int n = n4 * 4 + c;
                    const unsigned v = pack2((&w0.x)[c], (&w1.x)[c]);
                    B32[n * 32 + (((k2 >> 2) ^ (n & 15)) * 4) + (k2 & 3)] = v;
                }
            }
        }
        __syncthreads();

        f16x8 a2f[4];
        #pragma unroll
        for (int kst = 0; kst < 4; ++kst)
            a2f[kst] = *(const f16x8*)&A2[mrow * 128 + (((kst * 4 + (l >> 4)) ^ (l & 15)) * 8)];

        #pragma unroll 2
        for (int nt = 0; nt < 16; ++nt) {
            f32x4 acc = {0.f, 0.f, 0.f, 0.f};
            #pragma unroll
            for (int kst = 0; kst < 4; ++kst) {
                const f16x8 bf = *(const f16x8*)&Bs[(nt * 16 + (l & 15)) * 128
                                    + (((kst * 4 + (l >> 4)) ^ (l & 15)) * 8)];
                acc = __builtin_amdgcn_mfma_f32_16x16x32_f16(a2f[kst], bf, acc, 0, 0, 0);
            }
            const int col = nt * 16 + (l & 15);
            if (ch == 0) {
                const float ba = ba1[col], wa = wa2[col];
                #pragma unroll
                for (int i = 0; i < 4; ++i)
                    rs[i] += fmaxf(acc[i] + ba, 0.f) * wa;
            } else if (ch == 1) {
                const float bd = bd1[col];
                #pragma unroll
                for (int i = 0; i < 4; ++i) {
                    const int row = w * 16 + (l >> 4) * 4 + i;
                    Ai_u[(r0 + row) * HID + col] = h_bits(acc[i] + bd);
                }
            } else {
                #pragma unroll
                for (int i = 0; i < 4; ++i) {
                    const int row = w * 16 + (l >> 4) * 4 + i;
                    Aj_u[(r0 + row) * HID + col] = h_bits(acc[i]);
                }
            }
        }

        if (ch == 0) {
            #pragma unroll
            for (int i = 0; i < 4; ++i) {
                rs[i] += __shfl_xor(rs[i], 1);
                rs[i] += __shfl_xor(rs[i], 2);
                rs[i] += __shfl_xor(rs[i], 4);
                rs[i] += __shfl_xor(rs[i], 8);
            }
            if ((l & 15) == 0) {
                #pragma unroll
                for (int i = 0; i < 4; ++i)
                    score_s[w * 16 + (l >> 4) * 4 + i] = rs[i];
            }
        }
        __syncthreads();     // Bs reads done; (ch0) score_s ready
        if (ch == 0 && tid < 64)
            score[r0 + tid] = score_s[tid];   // ba2 dropped: softmax shift-inv
    }
    (void)ba2;
}

// ---------------------------------------------------------------------------
// K2: pairwise decoder (f16 inputs) + fused softmax. grid (145, 4). Proven.
// ---------------------------------------------------------------------------
__global__ __launch_bounds__(256) void pair_sm_kernel(
    const __half* __restrict__ Ai, const __half* __restrict__ Aj,
    const float* __restrict__ wd2, const float* __restrict__ bd2,
    const float* __restrict__ score, float* __restrict__ att,
    float* __restrict__ p)
{
    const int tid = threadIdx.x;
    const int b   = blockIdx.y;

    if (blockIdx.x == 144) {     // softmax for batch b
        __shared__ float red[8];
        const int t = tid;
        const float v0 = score[b * NCITY + t];
        const bool  h2v = (t < NCITY - 256);
        const float v1 = h2v ? score[b * NCITY + 256 + t] : -3.4e38f;
        float m = fmaxf(v0, v1);
        #pragma unroll
        for (int off = 32; off > 0; off >>= 1)
            m = fmaxf(m, __shfl_down(m, off));
        if ((t & 63) == 0) red[t >> 6] = m;
        __syncthreads();
        m = fmaxf(fmaxf(red[0], red[1]), fmaxf(red[2], red[3]));
        const float e0 = __expf(v0 - m);
        const float e1 = h2v ? __expf(v1 - m) : 0.f;
        float s = e0 + e1;
        #pragma unroll
        for (int off = 32; off > 0; off >>= 1)
            s += __shfl_down(s, off);
        if ((t & 63) == 0) red[4 + (t >> 6)] = s;
        __syncthreads();
        s = red[4] + red[5] + red[6] + red[7];
        att[b * NCITY + t] = e0 / s;
        if (h2v) att[b * NCITY + 256 + t] = e1 / s;
        return;
    }

    __shared__ __half ai_s[32 * HID];    // 16 KB
    __shared__ __half aj_s[32 * HID];    // 16 KB
    __shared__ unsigned wd2h[HID / 2];   // 512 B

    const int i0 = (blockIdx.x / 12) * 32;
    const int j0 = (blockIdx.x % 12) * 32;

    if (tid < HID / 2) {
        const float2 w2 = *(const float2*)&wd2[tid * 2];
        wd2h[tid] = pack2(w2.x, w2.y);
    }

    for (int u = tid; u < 32 * 32; u += 256) {
        const int r = u >> 5, s = u & 31;
        const int su = (s ^ (r & 15)) * 8;
        *(float4*)&ai_s[r * HID + su] =
            *(const float4*)&Ai[(b * NCITY + i0 + r) * HID + s * 8];
        *(float4*)&aj_s[r * HID + su] =
            *(const float4*)&Aj[(b * NCITY + j0 + r) * HID + s * 8];
    }
    __syncthreads();

    const int tx = tid & 15;
    const int ty = tid >> 4;

    unsigned a00A = 0u, a00B = 0u, a01A = 0u, a01B = 0u;
    unsigned a10A = 0u, a10B = 0u, a11A = 0u, a11B = 0u;

    #pragma unroll 4
    for (int k8 = 0; k8 < 32; ++k8) {
        const int ci = (k8 ^ ty) * 8;
        const int cj = (k8 ^ tx) * 8;
        H8 x0, x1, y0, y1;
        x0.f4 = *(const float4*)&ai_s[ ty       * HID + ci];
        x1.f4 = *(const float4*)&ai_s[(ty + 16) * HID + ci];
        y0.f4 = *(const float4*)&aj_s[ tx       * HID + cj];
        y1.f4 = *(const float4*)&aj_s[(tx + 16) * HID + cj];

        #pragma unroll
        for (int q = 0; q < 4; ++q) {
            const unsigned w = wd2h[k8 * 4 + q];
            const unsigned t00 = pk_max0(pk_add(x0.u[q], y0.u[q]));
            const unsigned t01 = pk_max0(pk_add(x0.u[q], y1.u[q]));
            const unsigned t10 = pk_max0(pk_add(x1.u[q], y0.u[q]));
            const unsigned t11 = pk_max0(pk_add(x1.u[q], y1.u[q]));
            if (q < 2) {
                a00A = pk_fma(t00, w, a00A);
                a01A = pk_fma(t01, w, a01A);
                a10A = pk_fma(t10, w, a10A);
                a11A = pk_fma(t11, w, a11A);
            } else {
                a00B = pk_fma(t00, w, a00B);
                a01B = pk_fma(t01, w, a01B);
                a10B = pk_fma(t10, w, a10B);
                a11B = pk_fma(t11, w, a11B);
            }
        }
    }

    const float bd = bd2[0];
    float accs[2][2];
    accs[0][0] = sum2(a00A) + sum2(a00B);
    accs[0][1] = sum2(a01A) + sum2(a01B);
    accs[1][0] = sum2(a10A) + sum2(a10B);
    accs[1][1] = sum2(a11A) + sum2(a11B);

    #pragma unroll
    for (int ii = 0; ii < 2; ++ii) {
        #pragma unroll
        for (int jj = 0; jj < 2; ++jj) {
            const int gi = i0 + ty + ii * 16;
            const int gj = j0 + tx + jj * 16;
            const float v = 1.f / (1.f + __expf(-(accs[ii][jj] + bd)));
            p[(b * NCITY + gi) * NCITY + gj] = (gi == gj) ? 0.f : v;
        }
    }
}

// ---------------------------------------------------------------------------
extern "C" void kernel_launch(void* const* d_in, const int* in_sizes, int n_in,
                              void* d_out, int out_size, void* d_ws, size_t ws_size,
                              hipStream_t stream)
{
    const float* cities = (const float*)d_in[0];
    const float* We1    = (const float*)d_in[1];
    const float* be1    = (const float*)d_in[2];
    const float* We2    = (const float*)d_in[3];
    const float* be2    = (const float*)d_in[4];
    const float* Wa1    = (const float*)d_in[5];
    const float* ba1    = (const float*)d_in[6];
    const float* wa2    = (const float*)d_in[7];
    const float* ba2    = (const float*)d_in[8];
    const float* Wd1    = (const float*)d_in[9];
    const float* bd1    = (const float*)d_in[10];
    const float* wd2    = (const float*)d_in[11];
    const float* bd2    = (const float*)d_in[12];

    float* out_att = (float*)d_out;                 // [4,384]
    float* out_p   = out_att + M_TOT;               // [4,384,384]

    float* score = (float*)d_ws;                    // 1536 f32
    u16*   Ai_u  = (u16*)(score + M_TOT);           // 1536*256 u16
    u16*   Aj_u  = Ai_u + M_TOT * HID;              // 1536*256 u16

    encoder_mfma<<<24, 256, 0, stream>>>(
        cities, We1, be1, We2, be2, Wa1, ba1, wa2, ba2, Wd1, bd1,
        score, Ai_u, Aj_u);

    pair_sm_kernel<<<dim3(145, BATCH), 256, 0, stream>>>(
        (const __half*)Ai_u, (const __half*)Aj_u, wd2, bd2,
        score, out_att, out_p);
}

// Round 19
// 33.747 us; speedup vs baseline: 1.5055x; 1.5055x over previous
//
#include <hip/hip_runtime.h>
#include <hip/hip_fp16.h>

#define NCITY 384
#define BATCH 4
#define DIM   128
#define HID   256
#define M_TOT (BATCH * NCITY)   // 1536
#define TR    3                 // rows per block -> 512 blocks = 2 blocks/CU

// ---------------------------------------------------------------------------
// K1: streaming encoder (R16 structure + explicit register double-buffered
// weight prefetch: 4-8 wave-loads in flight instead of ~1).
// ---------------------------------------------------------------------------
__device__ __forceinline__ void chunk_stream(
    const float* __restrict__ W,          // [128][256] row-major, global
    const float (*emb_s)[DIM], float* scr, int tid, float outr[TR])
{
    const int c4 = tid & 63;              // 4 output cols: 4*c4
    const int wv = tid >> 6;              // k-split 4: 32 k each
    const int k0 = wv * 32;
    const float* Wb = W + k0 * HID + c4 * 4;

    float4 acc[TR];
    #pragma unroll
    for (int rr = 0; rr < TR; ++rr) acc[rr] = make_float4(0.f, 0.f, 0.f, 0.f);

    float4 wb0[4], wb1[4];
    #pragma unroll
    for (int kk = 0; kk < 4; ++kk) wb0[kk] = *(const float4*)&Wb[kk * HID];
    #pragma unroll
    for (int kk = 0; kk < 4; ++kk) wb1[kk] = *(const float4*)&Wb[(4 + kk) * HID];

    #pragma unroll
    for (int kb = 0; kb < 32; kb += 8) {
        {   // consume wb0 (k = kb .. kb+3)
            float4 ev[TR];
            #pragma unroll
            for (int rr = 0; rr < TR; ++rr)
                ev[rr] = *(const float4*)&emb_s[rr][k0 + kb];
            #pragma unroll
            for (int kk = 0; kk < 4; ++kk) {
                #pragma unroll
                for (int rr = 0; rr < TR; ++rr) {
                    const float e = ((const float*)&ev[rr])[kk];
                    acc[rr].x = fmaf(e, wb0[kk].x, acc[rr].x);
                    acc[rr].y = fmaf(e, wb0[kk].y, acc[rr].y);
                    acc[rr].z = fmaf(e, wb0[kk].z, acc[rr].z);
                    acc[rr].w = fmaf(e, wb0[kk].w, acc[rr].w);
                }
            }
        }
        if (kb + 8 < 32) {
            #pragma unroll
            for (int kk = 0; kk < 4; ++kk)
                wb0[kk] = *(const float4*)&Wb[(kb + 8 + kk) * HID];
        }
        {   // consume wb1 (k = kb+4 .. kb+7)
            float4 ev[TR];
            #pragma unroll
            for (int rr = 0; rr < TR; ++rr)
                ev[rr] = *(const float4*)&emb_s[rr][k0 + kb + 4];
            #pragma unroll
            for (int kk = 0; kk < 4; ++kk) {
                #pragma unroll
                for (int rr = 0; rr < TR; ++rr) {
                    const float e = ((const float*)&ev[rr])[kk];
                    acc[rr].x = fmaf(e, wb1[kk].x, acc[rr].x);
                    acc[rr].y = fmaf(e, wb1[kk].y, acc[rr].y);
                    acc[rr].z = fmaf(e, wb1[kk].z, acc[rr].z);
                    acc[rr].w = fmaf(e, wb1[kk].w, acc[rr].w);
                }
            }
        }
        if (kb + 12 < 32) {
            #pragma unroll
            for (int kk = 0; kk < 4; ++kk)
                wb1[kk] = *(const float4*)&Wb[(kb + 12 + kk) * HID];
        }
    }
    __syncthreads();                      // prior scr readers done
    #pragma unroll
    for (int rr = 0; rr < TR; ++rr)
        *(float4*)&scr[(wv * TR + rr) * HID + c4 * 4] = acc[rr];
    __syncthreads();
    #pragma unroll
    for (int rr = 0; rr < TR; ++rr)
        outr[rr] = scr[(0 * TR + rr) * HID + tid] + scr[(1 * TR + rr) * HID + tid]
                 + scr[(2 * TR + rr) * HID + tid] + scr[(3 * TR + rr) * HID + tid];
}

__global__ __launch_bounds__(256, 2) void encoder_stream(
    const float* __restrict__ cities,
    const float* __restrict__ We1, const float* __restrict__ be1,
    const float* __restrict__ We2, const float* __restrict__ be2,
    const float* __restrict__ Wa1, const float* __restrict__ ba1,
    const float* __restrict__ wa2, const float* __restrict__ ba2,
    const float* __restrict__ Wd1, const float* __restrict__ bd1,
    float* __restrict__ score, float* __restrict__ Ai, float* __restrict__ Aj)
{
    __shared__ float h1_s[TR][HID];       // 3 KB
    __shared__ float emb_s[TR][DIM];      // 1.5 KB
    __shared__ float scr[4 * TR * HID];   // 12 KB reduce scratch
    __shared__ float red2[4][TR];

    const int tid = threadIdx.x;
    const int r0  = blockIdx.x * TR;

    // ---- h1 = relu(cities @ We1 + be1); thread owns k = tid ----------------
    {
        const float w0 = We1[tid], w1 = We1[HID + tid], b1v = be1[tid];
        #pragma unroll
        for (int rr = 0; rr < TR; ++rr) {
            const float cxx = cities[(r0 + rr) * 2];
            const float cyy = cities[(r0 + rr) * 2 + 1];
            h1_s[rr][tid] = fmaxf(fmaf(cxx, w0, fmaf(cyy, w1, b1v)), 0.f);
        }
    }
    __syncthreads();

    // ---- emb = h1 @ We2 + be2 (k-split 8, double-buffered weight stream) ---
    {
        const int d4 = tid & 31;          // 4 cols: 4*d4
        const int k0 = (tid >> 5) * 32;   // 8 k-groups
        const float* Wb = We2 + k0 * DIM + d4 * 4;
        float4 acc[TR];
        #pragma unroll
        for (int rr = 0; rr < TR; ++rr) acc[rr] = make_float4(0.f, 0.f, 0.f, 0.f);

        float4 wb0[4], wb1[4];
        #pragma unroll
        for (int kk = 0; kk < 4; ++kk) wb0[kk] = *(const float4*)&Wb[kk * DIM];
        #pragma unroll
        for (int kk = 0; kk < 4; ++kk) wb1[kk] = *(const float4*)&Wb[(4 + kk) * DIM];

        #pragma unroll
        for (int kb = 0; kb < 32; kb += 8) {
            {
                float4 hv[TR];
                #pragma unroll
                for (int rr = 0; rr < TR; ++rr)
                    hv[rr] = *(const float4*)&h1_s[rr][k0 + kb];
                #pragma unroll
                for (int kk = 0; kk < 4; ++kk) {
                    #pragma unroll
                    for (int rr = 0; rr < TR; ++rr) {
                        const float h = ((const float*)&hv[rr])[kk];
                        acc[rr].x = fmaf(h, wb0[kk].x, acc[rr].x);
                        acc[rr].y = fmaf(h, wb0[kk].y, acc[rr].y);
                        acc[rr].z = fmaf(h, wb0[kk].z, acc[rr].z);
                        acc[rr].w = fmaf(h, wb0[kk].w, acc[rr].w);
                    }
                }
            }
            if (kb + 8 < 32) {
                #pragma unroll
                for (int kk = 0; kk < 4; ++kk)
                    wb0[kk] = *(const float4*)&Wb[(kb + 8 + kk) * DIM];
            }
            {
                float4 hv[TR];
                #pragma unroll
                for (int rr = 0; rr < TR; ++rr)
                    hv[rr] = *(const float4*)&h1_s[rr][k0 + kb + 4];
                #pragma unroll
                for (int kk = 0; kk < 4; ++kk) {
                    #pragma unroll
                    for (int rr = 0; rr < TR; ++rr) {
                        const float h = ((const float*)&hv[rr])[kk];
                        acc[rr].x = fmaf(h, wb1[kk].x, acc[rr].x);
                        acc[rr].y = fmaf(h, wb1[kk].y, acc[rr].y);
                        acc[rr].z = fmaf(h, wb1[kk].z, acc[rr].z);
                        acc[rr].w = fmaf(h, wb1[kk].w, acc[rr].w);
                    }
                }
            }
            if (kb + 12 < 32) {
                #pragma unroll
                for (int kk = 0; kk < 4; ++kk)
                    wb1[kk] = *(const float4*)&Wb[(kb + 12 + kk) * DIM];
            }
        }
        #pragma unroll
        for (int rr = 0; rr < TR; ++rr) {
            acc[rr].x += __shfl_xor(acc[rr].x, 32);
            acc[rr].y += __shfl_xor(acc[rr].y, 32);
            acc[rr].z += __shfl_xor(acc[rr].z, 32);
            acc[rr].w += __shfl_xor(acc[rr].w, 32);
        }
        if ((tid & 63) < 32) {
            const int wv = tid >> 6;
            #pragma unroll
            for (int rr = 0; rr < TR; ++rr)
                *(float4*)&scr[(wv * TR + rr) * DIM + d4 * 4] = acc[rr];
        }
        __syncthreads();
        for (int o = tid; o < TR * DIM; o += 256) {
            const int rr = o >> 7, d = o & (DIM - 1);
            emb_s[rr][d] = scr[(0 * TR + rr) * DIM + d] + scr[(1 * TR + rr) * DIM + d]
                         + scr[(2 * TR + rr) * DIM + d] + scr[(3 * TR + rr) * DIM + d]
                         + be2[d];
        }
        __syncthreads();
    }

    float o6[TR];

    // ---- Wa1 -> attention scores -------------------------------------------
    chunk_stream(Wa1, emb_s, scr, tid, o6);
    {
        const float ba1v = ba1[tid], wa2v = wa2[tid];
        const int wv = tid >> 6;
        #pragma unroll
        for (int rr = 0; rr < TR; ++rr) {
            float v = fmaxf(o6[rr] + ba1v, 0.f) * wa2v;
            #pragma unroll
            for (int off = 32; off > 0; off >>= 1)
                v += __shfl_down(v, off);
            if ((tid & 63) == 0) red2[wv][rr] = v;
        }
        __syncthreads();
        if (tid < TR)
            score[r0 + tid] = red2[0][tid] + red2[1][tid] + red2[2][tid] + red2[3][tid];
        // ba2 dropped: softmax is shift-invariant
    }

    // ---- Wd1 rows 0..127 -> Ai ---------------------------------------------
    chunk_stream(Wd1, emb_s, scr, tid, o6);
    {
        const float bd1v = bd1[tid];
        #pragma unroll
        for (int rr = 0; rr < TR; ++rr)
            Ai[(r0 + rr) * HID + tid] = o6[rr] + bd1v;
    }

    // ---- Wd1 rows 128..255 -> Aj -------------------------------------------
    chunk_stream(Wd1 + DIM * HID, emb_s, scr, tid, o6);
    #pragma unroll
    for (int rr = 0; rr < TR; ++rr)
        Aj[(r0 + rr) * HID + tid] = o6[rr];
    (void)ba2;
}

// ---------------------------------------------------------------------------
// Packed f16 helpers (raw VOP3P; ROCm header __hmax2 broken on gfx950).
// ---------------------------------------------------------------------------
__device__ __forceinline__ unsigned pk_add(unsigned a, unsigned b) {
    unsigned r; asm("v_pk_add_f16 %0, %1, %2" : "=v"(r) : "v"(a), "v"(b)); return r;
}
__device__ __forceinline__ unsigned pk_max0(unsigned a) {
    unsigned r; asm("v_pk_max_f16 %0, %1, %2" : "=v"(r) : "v"(a), "v"(0u)); return r;
}
__device__ __forceinline__ unsigned pk_fma(unsigned a, unsigned b, unsigned c) {
    unsigned r; asm("v_pk_fma_f16 %0, %1, %2, %3" : "=v"(r) : "v"(a), "v"(b), "v"(c)); return r;
}
__device__ __forceinline__ unsigned pack2(float a, float b) {
    union { __half2 h2; unsigned u; } c;
    c.h2 = __float22half2_rn(make_float2(a, b));
    return c.u;
}
__device__ __forceinline__ float sum2(unsigned u) {
    union { unsigned u; __half2 h2; } c; c.u = u;
    return __low2float(c.h2) + __high2float(c.h2);
}
union H8 { float4 f4; unsigned u[4]; };

// ---------------------------------------------------------------------------
// K2: pairwise decoder in packed f16 + fused softmax (verbatim R16 — proven).
// ---------------------------------------------------------------------------
__global__ __launch_bounds__(256) void pair_sm_kernel(
    const float* __restrict__ Ai, const float* __restrict__ Aj,
    const float* __restrict__ wd2, const float* __restrict__ bd2,
    const float* __restrict__ score, float* __restrict__ att,
    float* __restrict__ p)
{
    const int tid = threadIdx.x;
    const int b   = blockIdx.y;

    if (blockIdx.x == 144) {     // ---- softmax block for batch b ------------
        __shared__ float red[8];
        const int t = tid;
        const float v0 = score[b * NCITY + t];
        const bool  h2v = (t < NCITY - 256);
        const float v1 = h2v ? score[b * NCITY + 256 + t] : -3.4e38f;
        float m = fmaxf(v0, v1);
        #pragma unroll
        for (int off = 32; off > 0; off >>= 1)
            m = fmaxf(m, __shfl_down(m, off));
        if ((t & 63) == 0) red[t >> 6] = m;
        __syncthreads();
        m = fmaxf(fmaxf(red[0], red[1]), fmaxf(red[2], red[3]));
        const float e0 = __expf(v0 - m);
        const float e1 = h2v ? __expf(v1 - m) : 0.f;
        float s = e0 + e1;
        #pragma unroll
        for (int off = 32; off > 0; off >>= 1)
            s += __shfl_down(s, off);
        if ((t & 63) == 0) red[4 + (t >> 6)] = s;
        __syncthreads();
        s = red[4] + red[5] + red[6] + red[7];
        att[b * NCITY + t] = e0 / s;
        if (h2v) att[b * NCITY + 256 + t] = e1 / s;
        return;
    }

    // ---- pair tile ---------------------------------------------------------
    __shared__ __half ai_s[32 * HID];    // 16 KB
    __shared__ __half aj_s[32 * HID];    // 16 KB
    __shared__ unsigned wd2h[HID / 2];   // 512 B

    const int i0 = (blockIdx.x / 12) * 32;
    const int j0 = (blockIdx.x % 12) * 32;

    if (tid < HID / 2) {
        const float2 w2 = *(const float2*)&wd2[tid * 2];
        wd2h[tid] = pack2(w2.x, w2.y);
    }

    for (int u = tid; u < 32 * 32; u += 256) {
        const int r = u >> 5, s = u & 31;
        const int su = (s ^ (r & 15)) * 8;
        {
            const int g = (b * NCITY + i0 + r) * HID + s * 8;
            const float4 f0 = *(const float4*)&Ai[g];
            const float4 f1 = *(const float4*)&Ai[g + 4];
            H8 pk;
            pk.u[0] = pack2(f0.x, f0.y);
            pk.u[1] = pack2(f0.z, f0.w);
            pk.u[2] = pack2(f1.x, f1.y);
            pk.u[3] = pack2(f1.z, f1.w);
            *(float4*)&ai_s[r * HID + su] = pk.f4;
        }
        {
            const int g = (b * NCITY + j0 + r) * HID + s * 8;
            const float4 f0 = *(const float4*)&Aj[g];
            const float4 f1 = *(const float4*)&Aj[g + 4];
            H8 pk;
            pk.u[0] = pack2(f0.x, f0.y);
            pk.u[1] = pack2(f0.z, f0.w);
            pk.u[2] = pack2(f1.x, f1.y);
            pk.u[3] = pack2(f1.z, f1.w);
            *(float4*)&aj_s[r * HID + su] = pk.f4;
        }
    }
    __syncthreads();

    const int tx = tid & 15;
    const int ty = tid >> 4;

    unsigned a00A = 0u, a00B = 0u, a01A = 0u, a01B = 0u;
    unsigned a10A = 0u, a10B = 0u, a11A = 0u, a11B = 0u;

    #pragma unroll 4
    for (int k8 = 0; k8 < 32; ++k8) {
        const int ci = (k8 ^ ty) * 8;
        const int cj = (k8 ^ tx) * 8;
        H8 x0, x1, y0, y1;
        x0.f4 = *(const float4*)&ai_s[ ty       * HID + ci];
        x1.f4 = *(const float4*)&ai_s[(ty + 16) * HID + ci];
        y0.f4 = *(const float4*)&aj_s[ tx       * HID + cj];
        y1.f4 = *(const float4*)&aj_s[(tx + 16) * HID + cj];

        #pragma unroll
        for (int q = 0; q < 4; ++q) {
            const unsigned w = wd2h[k8 * 4 + q];
            const unsigned t00 = pk_max0(pk_add(x0.u[q], y0.u[q]));
            const unsigned t01 = pk_max0(pk_add(x0.u[q], y1.u[q]));
            const unsigned t10 = pk_max0(pk_add(x1.u[q], y0.u[q]));
            const unsigned t11 = pk_max0(pk_add(x1.u[q], y1.u[q]));
            if (q < 2) {
                a00A = pk_fma(t00, w, a00A);
                a01A = pk_fma(t01, w, a01A);
                a10A = pk_fma(t10, w, a10A);
                a11A = pk_fma(t11, w, a11A);
            } else {
                a00B = pk_fma(t00, w, a00B);
                a01B = pk_fma(t01, w, a01B);
                a10B = pk_fma(t10, w, a10B);
                a11B = pk_fma(t11, w, a11B);
            }
        }
    }

    const float bd = bd2[0];
    float accs[2][2];
    accs[0][0] = sum2(a00A) + sum2(a00B);
    accs[0][1] = sum2(a01A) + sum2(a01B);
    accs[1][0] = sum2(a10A) + sum2(a10B);
    accs[1][1] = sum2(a11A) + sum2(a11B);

    #pragma unroll
    for (int ii = 0; ii < 2; ++ii) {
        #pragma unroll
        for (int jj = 0; jj < 2; ++jj) {
            const int gi = i0 + ty + ii * 16;
            const int gj = j0 + tx + jj * 16;
            const float v = 1.f / (1.f + __expf(-(accs[ii][jj] + bd)));
            p[(b * NCITY + gi) * NCITY + gj] = (gi == gj) ? 0.f : v;
        }
    }
}

// ---------------------------------------------------------------------------
extern "C" void kernel_launch(void* const* d_in, const int* in_sizes, int n_in,
                              void* d_out, int out_size, void* d_ws, size_t ws_size,
                              hipStream_t stream)
{
    const float* cities = (const float*)d_in[0];
    const float* We1    = (const float*)d_in[1];
    const float* be1    = (const float*)d_in[2];
    const float* We2    = (const float*)d_in[3];
    const float* be2    = (const float*)d_in[4];
    const float* Wa1    = (const float*)d_in[5];
    const float* ba1    = (const float*)d_in[6];
    const float* wa2    = (const float*)d_in[7];
    const float* ba2    = (const float*)d_in[8];
    const float* Wd1    = (const float*)d_in[9];
    const float* bd1    = (const float*)d_in[10];
    const float* wd2    = (const float*)d_in[11];
    const float* bd2    = (const float*)d_in[12];

    float* out_att = (float*)d_out;                 // [4,384]
    float* out_p   = out_att + M_TOT;               // [4,384,384]

    float* score = (float*)d_ws;                    // 1536
    float* Ai    = score + M_TOT;                   // 1536*256
    float* Aj    = Ai + M_TOT * HID;                // 1536*256

    encoder_stream<<<M_TOT / TR, 256, 0, stream>>>(
        cities, We1, be1, We2, be2, Wa1, ba1, wa2, ba2, Wd1, bd1,
        score, Ai, Aj);

    pair_sm_kernel<<<dim3(145, BATCH), 256, 0, stream>>>(
        Ai, Aj, wd2, bd2, score, out_att, out_p);
}

// Round 20
// 33.190 us; speedup vs baseline: 1.5307x; 1.0168x over previous
//
#include <hip/hip_runtime.h>
#include <hip/hip_fp16.h>

#define NCITY 384
#define BATCH 4
#define DIM   128
#define HID   256
#define M_TOT (BATCH * NCITY)   // 1536
#define TR    6                 // rows per block -> 256 blocks x 512 threads

// ---------------------------------------------------------------------------
// K1: streaming encoder, 512-thread blocks: 256 blocks (minimal 128 MB weight
// traffic) AND 8 waves/block = 2 waves/SIMD (latency hiding). LDS 58.5 KB.
// ---------------------------------------------------------------------------
__global__ __launch_bounds__(512, 1) void encoder_stream(
    const float* __restrict__ cities,
    const float* __restrict__ We1, const float* __restrict__ be1,
    const float* __restrict__ We2, const float* __restrict__ be2,
    const float* __restrict__ Wa1, const float* __restrict__ ba1,
    const float* __restrict__ wa2, const float* __restrict__ ba2,
    const float* __restrict__ Wd1, const float* __restrict__ bd1,
    float* __restrict__ score, float* __restrict__ Ai, float* __restrict__ Aj)
{
    __shared__ float h1_s[TR][HID];       // 6 KB
    __shared__ float emb_s[TR][DIM];      // 3 KB
    __shared__ float scr[12288];          // 48 KB (16 or 8 reduce slabs)
    __shared__ float red2[4][TR];

    const int tid = threadIdx.x;
    const int r0  = blockIdx.x * TR;

    // ---- h1 = relu(cities @ We1 + be1); threads 0-255 own k = tid ----------
    if (tid < 256) {
        const float w0 = We1[tid], w1 = We1[HID + tid], b1v = be1[tid];
        #pragma unroll
        for (int rr = 0; rr < TR; ++rr) {
            const float cxx = cities[(r0 + rr) * 2];
            const float cyy = cities[(r0 + rr) * 2 + 1];
            h1_s[rr][tid] = fmaxf(fmaf(cxx, w0, fmaf(cyy, w1, b1v)), 0.f);
        }
    }
    __syncthreads();

    // ---- emb = h1 @ We2 + be2 : k-split 16 x 16k, 16 reduce slabs ----------
    {
        const int d4 = tid & 31;          // col-quad of 128
        const int ks = tid >> 5;          // 0..15
        const int k0 = ks * 16;
        float4 acc[TR];
        #pragma unroll
        for (int rr = 0; rr < TR; ++rr) acc[rr] = make_float4(0.f, 0.f, 0.f, 0.f);

        #pragma unroll
        for (int kb = 0; kb < 16; kb += 4) {
            float4 hv[TR];
            #pragma unroll
            for (int rr = 0; rr < TR; ++rr)
                hv[rr] = *(const float4*)&h1_s[rr][k0 + kb];
            #pragma unroll
            for (int kk = 0; kk < 4; ++kk) {
                const float4 w4 = *(const float4*)&We2[(k0 + kb + kk) * DIM + d4 * 4];
                #pragma unroll
                for (int rr = 0; rr < TR; ++rr) {
                    const float h = ((const float*)&hv[rr])[kk];
                    acc[rr].x = fmaf(h, w4.x, acc[rr].x);
                    acc[rr].y = fmaf(h, w4.y, acc[rr].y);
                    acc[rr].z = fmaf(h, w4.z, acc[rr].z);
                    acc[rr].w = fmaf(h, w4.w, acc[rr].w);
                }
            }
        }
        #pragma unroll
        for (int rr = 0; rr < TR; ++rr)
            *(float4*)&scr[(ks * TR + rr) * DIM + d4 * 4] = acc[rr];
        __syncthreads();
        for (int o = tid; o < TR * DIM; o += 512) {
            const int rr = o >> 7, d = o & (DIM - 1);
            float v = be2[d];
            #pragma unroll
            for (int s = 0; s < 16; ++s)
                v += scr[(s * TR + rr) * DIM + d];
            emb_s[rr][d] = v;
        }
        __syncthreads();
    }

    const int col = tid & 255;
    float o6[TR];

    // ==== chunk macro: W[128][256] streamed, k-split 8 x 16k, 8 slabs =======
#define CHUNK(W)                                                             \
    {                                                                        \
        const int c4 = tid & 63;                                             \
        const int wv = tid >> 6;          /* 0..7 */                         \
        const int k0 = wv * 16;                                              \
        float4 acc[TR];                                                      \
        _Pragma("unroll")                                                    \
        for (int rr = 0; rr < TR; ++rr) acc[rr] = make_float4(0.f,0.f,0.f,0.f); \
        _Pragma("unroll")                                                    \
        for (int kb = 0; kb < 16; kb += 4) {                                 \
            float4 ev[TR];                                                   \
            _Pragma("unroll")                                                \
            for (int rr = 0; rr < TR; ++rr)                                  \
                ev[rr] = *(const float4*)&emb_s[rr][k0 + kb];                \
            _Pragma("unroll")                                                \
            for (int kk = 0; kk < 4; ++kk) {                                 \
                const float4 w4 = *(const float4*)&(W)[(k0 + kb + kk) * HID + c4 * 4]; \
                _Pragma("unroll")                                            \
                for (int rr = 0; rr < TR; ++rr) {                            \
                    const float e = ((const float*)&ev[rr])[kk];             \
                    acc[rr].x = fmaf(e, w4.x, acc[rr].x);                    \
                    acc[rr].y = fmaf(e, w4.y, acc[rr].y);                    \
                    acc[rr].z = fmaf(e, w4.z, acc[rr].z);                    \
                    acc[rr].w = fmaf(e, w4.w, acc[rr].w);                    \
                }                                                            \
            }                                                                \
        }                                                                    \
        __syncthreads();                  /* prior scr readers done */       \
        _Pragma("unroll")                                                    \
        for (int rr = 0; rr < TR; ++rr)                                      \
            *(float4*)&scr[(wv * TR + rr) * HID + c4 * 4] = acc[rr];         \
        __syncthreads();                                                     \
        _Pragma("unroll")                                                    \
        for (int rr = 0; rr < TR; ++rr) {                                    \
            float v = 0.f;                                                   \
            _Pragma("unroll")                                                \
            for (int s = 0; s < 8; ++s)                                      \
                v += scr[(s * TR + rr) * HID + col];                         \
            o6[rr] = v;                                                      \
        }                                                                    \
    }

    // ---- Wa1 -> attention scores -------------------------------------------
    CHUNK(Wa1)
    {
        const float ba1v = ba1[col], wa2v = wa2[col];
        #pragma unroll
        for (int rr = 0; rr < TR; ++rr) {
            float v = fmaxf(o6[rr] + ba1v, 0.f) * wa2v;
            #pragma unroll
            for (int off = 32; off > 0; off >>= 1)
                v += __shfl_down(v, off);
            if ((tid & 63) == 0 && tid < 256) red2[tid >> 6][rr] = v;
        }
        __syncthreads();
        if (tid < TR)
            score[r0 + tid] = red2[0][tid] + red2[1][tid] + red2[2][tid] + red2[3][tid];
        // ba2 dropped: softmax is shift-invariant
    }

    // ---- Wd1 rows 0..127 -> Ai ---------------------------------------------
    CHUNK(Wd1)
    if (tid < 256) {
        const float bd1v = bd1[tid];
        #pragma unroll
        for (int rr = 0; rr < TR; ++rr)
            Ai[(r0 + rr) * HID + tid] = o6[rr] + bd1v;
    }

    // ---- Wd1 rows 128..255 -> Aj -------------------------------------------
    CHUNK(Wd1 + DIM * HID)
    if (tid < 256) {
        #pragma unroll
        for (int rr = 0; rr < TR; ++rr)
            Aj[(r0 + rr) * HID + tid] = o6[rr];
    }
    (void)ba2;
#undef CHUNK
}

// ---------------------------------------------------------------------------
// Packed f16 helpers (raw VOP3P; ROCm header __hmax2 broken on gfx950).
// ---------------------------------------------------------------------------
__device__ __forceinline__ unsigned pk_add(unsigned a, unsigned b) {
    unsigned r; asm("v_pk_add_f16 %0, %1, %2" : "=v"(r) : "v"(a), "v"(b)); return r;
}
__device__ __forceinline__ unsigned pk_max0(unsigned a) {
    unsigned r; asm("v_pk_max_f16 %0, %1, %2" : "=v"(r) : "v"(a), "v"(0u)); return r;
}
__device__ __forceinline__ unsigned pk_fma(unsigned a, unsigned b, unsigned c) {
    unsigned r; asm("v_pk_fma_f16 %0, %1, %2, %3" : "=v"(r) : "v"(a), "v"(b), "v"(c)); return r;
}
__device__ __forceinline__ unsigned pack2(float a, float b) {
    union { __half2 h2; unsigned u; } c;
    c.h2 = __float22half2_rn(make_float2(a, b));
    return c.u;
}
__device__ __forceinline__ float sum2(unsigned u) {
    union { unsigned u; __half2 h2; } c; c.u = u;
    return __low2float(c.h2) + __high2float(c.h2);
}
union H8 { float4 f4; unsigned u[4]; };

// ---------------------------------------------------------------------------
// K2: pairwise decoder in packed f16 + fused softmax (verbatim R16 — proven).
// ---------------------------------------------------------------------------
__global__ __launch_bounds__(256) void pair_sm_kernel(
    const float* __restrict__ Ai, const float* __restrict__ Aj,
    const float* __restrict__ wd2, const float* __restrict__ bd2,
    const float* __restrict__ score, float* __restrict__ att,
    float* __restrict__ p)
{
    const int tid = threadIdx.x;
    const int b   = blockIdx.y;

    if (blockIdx.x == 144) {     // ---- softmax block for batch b ------------
        __shared__ float red[8];
        const int t = tid;
        const float v0 = score[b * NCITY + t];
        const bool  h2v = (t < NCITY - 256);
        const float v1 = h2v ? score[b * NCITY + 256 + t] : -3.4e38f;
        float m = fmaxf(v0, v1);
        #pragma unroll
        for (int off = 32; off > 0; off >>= 1)
            m = fmaxf(m, __shfl_down(m, off));
        if ((t & 63) == 0) red[t >> 6] = m;
        __syncthreads();
        m = fmaxf(fmaxf(red[0], red[1]), fmaxf(red[2], red[3]));
        const float e0 = __expf(v0 - m);
        const float e1 = h2v ? __expf(v1 - m) : 0.f;
        float s = e0 + e1;
        #pragma unroll
        for (int off = 32; off > 0; off >>= 1)
            s += __shfl_down(s, off);
        if ((t & 63) == 0) red[4 + (t >> 6)] = s;
        __syncthreads();
        s = red[4] + red[5] + red[6] + red[7];
        att[b * NCITY + t] = e0 / s;
        if (h2v) att[b * NCITY + 256 + t] = e1 / s;
        return;
    }

    // ---- pair tile ---------------------------------------------------------
    __shared__ __half ai_s[32 * HID];    // 16 KB
    __shared__ __half aj_s[32 * HID];    // 16 KB
    __shared__ unsigned wd2h[HID / 2];   // 512 B

    const int i0 = (blockIdx.x / 12) * 32;
    const int j0 = (blockIdx.x % 12) * 32;

    if (tid < HID / 2) {
        const float2 w2 = *(const float2*)&wd2[tid * 2];
        wd2h[tid] = pack2(w2.x, w2.y);
    }

    for (int u = tid; u < 32 * 32; u += 256) {
        const int r = u >> 5, s = u & 31;
        const int su = (s ^ (r & 15)) * 8;
        {
            const int g = (b * NCITY + i0 + r) * HID + s * 8;
            const float4 f0 = *(const float4*)&Ai[g];
            const float4 f1 = *(const float4*)&Ai[g + 4];
            H8 pk;
            pk.u[0] = pack2(f0.x, f0.y);
            pk.u[1] = pack2(f0.z, f0.w);
            pk.u[2] = pack2(f1.x, f1.y);
            pk.u[3] = pack2(f1.z, f1.w);
            *(float4*)&ai_s[r * HID + su] = pk.f4;
        }
        {
            const int g = (b * NCITY + j0 + r) * HID + s * 8;
            const float4 f0 = *(const float4*)&Aj[g];
            const float4 f1 = *(const float4*)&Aj[g + 4];
            H8 pk;
            pk.u[0] = pack2(f0.x, f0.y);
            pk.u[1] = pack2(f0.z, f0.w);
            pk.u[2] = pack2(f1.x, f1.y);
            pk.u[3] = pack2(f1.z, f1.w);
            *(float4*)&aj_s[r * HID + su] = pk.f4;
        }
    }
    __syncthreads();

    const int tx = tid & 15;
    const int ty = tid >> 4;

    unsigned a00A = 0u, a00B = 0u, a01A = 0u, a01B = 0u;
    unsigned a10A = 0u, a10B = 0u, a11A = 0u, a11B = 0u;

    #pragma unroll 4
    for (int k8 = 0; k8 < 32; ++k8) {
        const int ci = (k8 ^ ty) * 8;
        const int cj = (k8 ^ tx) * 8;
        H8 x0, x1, y0, y1;
        x0.f4 = *(const float4*)&ai_s[ ty       * HID + ci];
        x1.f4 = *(const float4*)&ai_s[(ty + 16) * HID + ci];
        y0.f4 = *(const float4*)&aj_s[ tx       * HID + cj];
        y1.f4 = *(const float4*)&aj_s[(tx + 16) * HID + cj];

        #pragma unroll
        for (int q = 0; q < 4; ++q) {
            const unsigned w = wd2h[k8 * 4 + q];
            const unsigned t00 = pk_max0(pk_add(x0.u[q], y0.u[q]));
            const unsigned t01 = pk_max0(pk_add(x0.u[q], y1.u[q]));
            const unsigned t10 = pk_max0(pk_add(x1.u[q], y0.u[q]));
            const unsigned t11 = pk_max0(pk_add(x1.u[q], y1.u[q]));
            if (q < 2) {
                a00A = pk_fma(t00, w, a00A);
                a01A = pk_fma(t01, w, a01A);
                a10A = pk_fma(t10, w, a10A);
                a11A = pk_fma(t11, w, a11A);
            } else {
                a00B = pk_fma(t00, w, a00B);
                a01B = pk_fma(t01, w, a01B);
                a10B = pk_fma(t10, w, a10B);
                a11B = pk_fma(t11, w, a11B);
            }
        }
    }

    const float bd = bd2[0];
    float accs[2][2];
    accs[0][0] = sum2(a00A) + sum2(a00B);
    accs[0][1] = sum2(a01A) + sum2(a01B);
    accs[1][0] = sum2(a10A) + sum2(a10B);
    accs[1][1] = sum2(a11A) + sum2(a11B);

    #pragma unroll
    for (int ii = 0; ii < 2; ++ii) {
        #pragma unroll
        for (int jj = 0; jj < 2; ++jj) {
            const int gi = i0 + ty + ii * 16;
            const int gj = j0 + tx + jj * 16;
            const float v = 1.f / (1.f + __expf(-(accs[ii][jj] + bd)));
            p[(b * NCITY + gi) * NCITY + gj] = (gi == gj) ? 0.f : v;
        }
    }
}

// ---------------------------------------------------------------------------
extern "C" void kernel_launch(void* const* d_in, const int* in_sizes, int n_in,
                              void* d_out, int out_size, void* d_ws, size_t ws_size,
                              hipStream_t stream)
{
    const float* cities = (const float*)d_in[0];
    const float* We1    = (const float*)d_in[1];
    const float* be1    = (const float*)d_in[2];
    const float* We2    = (const float*)d_in[3];
    const float* be2    = (const float*)d_in[4];
    const float* Wa1    = (const float*)d_in[5];
    const float* ba1    = (const float*)d_in[6];
    const float* wa2    = (const float*)d_in[7];
    const float* ba2    = (const float*)d_in[8];
    const float* Wd1    = (const float*)d_in[9];
    const float* bd1    = (const float*)d_in[10];
    const float* wd2    = (const float*)d_in[11];
    const float* bd2    = (const float*)d_in[12];

    float* out_att = (float*)d_out;                 // [4,384]
    float* out_p   = out_att + M_TOT;               // [4,384,384]

    float* score = (float*)d_ws;                    // 1536
    float* Ai    = score + M_TOT;                   // 1536*256
    float* Aj    = Ai + M_TOT * HID;                // 1536*256

    encoder_stream<<<M_TOT / TR, 512, 0, stream>>>(
        cities, We1, be1, We2, be2, Wa1, ba1, wa2, ba2, Wd1, bd1,
        score, Ai, Aj);

    pair_sm_kernel<<<dim3(145, BATCH), 256, 0, stream>>>(
        Ai, Aj, wd2, bd2, score, out_att, out_p);
}